// Round 1
// baseline (189.370 us; speedup 1.0000x reference)
//
#include <hip/hip_runtime.h>
#include <hip/hip_bf16.h>

// PercolationM: per-batch-element 256-bin histogram of [B,256,32,32] int32,
// output max bin count per batch element as float32. B=128, N=262144/batch.
//
// Strategy:
//   k1: 4 blocks per batch element. Each block: 32-replica LDS histogram with
//       bank-exclusive layout hist[bin*32 + lane%32] (lane i always hits bank
//       i%32 -> zero bank conflicts). int4 coalesced loads. Epilogue sums the
//       32 replicas per bin (rotated index, conflict-free) and atomicAdds into
//       a global per-batch histogram in d_ws.
//   k2: per-batch max-reduce over 256 bins -> float32.

#define NUM_BINS 256
#define NREP     32            // sub-histogram replicas (one per bank)
#define BPB      4             // blocks per batch element
#define N_PER_B  (256 * 32 * 32)   // 262144 elements per batch element
#define CHUNK    (N_PER_B / BPB)   // 65536 elements per block
#define BLOCK1   1024

__global__ __launch_bounds__(BLOCK1) void
percolation_hist_kernel(const int* __restrict__ in, int* __restrict__ ghist) {
    __shared__ int lh[NUM_BINS * NREP];   // 32 KiB

    // zero LDS histogram
    for (int i = threadIdx.x; i < NUM_BINS * NREP; i += BLOCK1)
        lh[i] = 0;
    __syncthreads();

    const int batch = blockIdx.x / BPB;
    const int sub   = blockIdx.x % BPB;
    const int lane  = threadIdx.x & (NREP - 1);   // bank-exclusive replica id

    const int4* p = (const int4*)(in + (size_t)batch * N_PER_B + (size_t)sub * CHUNK);
    const int iters = CHUNK / 4 / BLOCK1;         // 16

#pragma unroll 4
    for (int i = 0; i < iters; ++i) {
        int4 v = p[(size_t)i * BLOCK1 + threadIdx.x];
        atomicAdd(&lh[v.x * NREP + lane], 1);
        atomicAdd(&lh[v.y * NREP + lane], 1);
        atomicAdd(&lh[v.z * NREP + lane], 1);
        atomicAdd(&lh[v.w * NREP + lane], 1);
    }
    __syncthreads();

    // Sum the 32 replicas per bin; rotate replica index by tid so all lanes of
    // a wave hit distinct banks ((j+tid)%32), then merge into global hist.
    if (threadIdx.x < NUM_BINS) {
        int s = 0;
#pragma unroll
        for (int j = 0; j < NREP; ++j)
            s += lh[threadIdx.x * NREP + ((j + threadIdx.x) & (NREP - 1))];
        atomicAdd(&ghist[batch * NUM_BINS + threadIdx.x], s);
    }
}

__global__ __launch_bounds__(NUM_BINS) void
percolation_max_kernel(const int* __restrict__ ghist, float* __restrict__ out) {
    const int batch = blockIdx.x;
    int v = ghist[batch * NUM_BINS + threadIdx.x];

    // wave (64-lane) max reduce
#pragma unroll
    for (int off = 32; off > 0; off >>= 1)
        v = max(v, __shfl_down(v, off, 64));

    __shared__ int wmax[NUM_BINS / 64];
    if ((threadIdx.x & 63) == 0)
        wmax[threadIdx.x >> 6] = v;
    __syncthreads();

    if (threadIdx.x == 0) {
        int m = wmax[0];
#pragma unroll
        for (int w = 1; w < NUM_BINS / 64; ++w)
            m = max(m, wmax[w]);
        out[batch] = (float)m;
    }
}

extern "C" void kernel_launch(void* const* d_in, const int* in_sizes, int n_in,
                              void* d_out, int out_size, void* d_ws, size_t ws_size,
                              hipStream_t stream) {
    const int* in   = (const int*)d_in[0];
    float*     out  = (float*)d_out;
    int*       hist = (int*)d_ws;                 // 128 * 256 * 4 B = 128 KiB

    const int B = out_size;                       // 128

    // ws is re-poisoned to 0xAA before every timed call — zero the histogram.
    hipMemsetAsync(hist, 0, (size_t)B * NUM_BINS * sizeof(int), stream);

    percolation_hist_kernel<<<B * BPB, BLOCK1, 0, stream>>>(in, hist);
    percolation_max_kernel<<<B, NUM_BINS, 0, stream>>>(hist, out);
}

// Round 2
// 188.016 us; speedup vs baseline: 1.0072x; 1.0072x over previous
//
#include <hip/hip_runtime.h>
#include <hip/hip_bf16.h>

// PercolationM: per-batch-element 256-bin histogram of [B,256,32,32] int32,
// output max bin count per batch element as float32. B=128, N=262144/batch.
//
// Round 2 strategy (vs R1): drop the ws memset + global atomic merge.
//   k1: 4 blocks per batch element, 1024 thr. Bank-exclusive 32-replica LDS
//       histogram (hist[bin*32 + lane&31] -> lane i always bank i%32, zero
//       conflicts). int4 coalesced loads. Epilogue: threads 0..255 sum the 32
//       replicas (rotated index, conflict-free) and store a plain partial
//       histogram to ws (fully overwritten -> no zeroing dispatch needed).
//   k2: per batch element, sum 4 partial hists (L2-resident) + max-reduce.

#define NUM_BINS 256
#define NREP     32                // sub-histogram replicas (one per bank)
#define BPB      4                 // blocks per batch element
#define N_PER_B  (256 * 32 * 32)   // 262144 elements per batch element
#define CHUNK    (N_PER_B / BPB)   // 65536 elements per block
#define BLOCK1   1024

__global__ __launch_bounds__(BLOCK1) void
percolation_hist_kernel(const int* __restrict__ in, int* __restrict__ part) {
    __shared__ int lh[NUM_BINS * NREP];   // 32 KiB

    for (int i = threadIdx.x; i < NUM_BINS * NREP; i += BLOCK1)
        lh[i] = 0;
    __syncthreads();

    const int lane = threadIdx.x & (NREP - 1);    // bank-exclusive replica id

    const int4* p = (const int4*)(in + (size_t)blockIdx.x * CHUNK);
    const int iters = CHUNK / 4 / BLOCK1;         // 16

#pragma unroll 4
    for (int i = 0; i < iters; ++i) {
        int4 v = p[(size_t)i * BLOCK1 + threadIdx.x];
        atomicAdd(&lh[v.x * NREP + lane], 1);
        atomicAdd(&lh[v.y * NREP + lane], 1);
        atomicAdd(&lh[v.z * NREP + lane], 1);
        atomicAdd(&lh[v.w * NREP + lane], 1);
    }
    __syncthreads();

    // Threads 0..255: sum 32 replicas per bin with rotated replica index
    // ((j+tid)&31 -> all lanes of a wave hit distinct banks), plain store.
    if (threadIdx.x < NUM_BINS) {
        int s = 0;
#pragma unroll
        for (int j = 0; j < NREP; ++j)
            s += lh[threadIdx.x * NREP + ((j + threadIdx.x) & (NREP - 1))];
        part[blockIdx.x * NUM_BINS + threadIdx.x] = s;
    }
}

__global__ __launch_bounds__(NUM_BINS) void
percolation_max_kernel(const int* __restrict__ part, float* __restrict__ out) {
    const int batch = blockIdx.x;
    const int bin   = threadIdx.x;

    const int* p = part + (size_t)batch * BPB * NUM_BINS;
    int v = 0;
#pragma unroll
    for (int s = 0; s < BPB; ++s)
        v += p[s * NUM_BINS + bin];

    // wave (64-lane) max reduce
#pragma unroll
    for (int off = 32; off > 0; off >>= 1)
        v = max(v, __shfl_down(v, off, 64));

    __shared__ int wmax[NUM_BINS / 64];
    if ((threadIdx.x & 63) == 0)
        wmax[threadIdx.x >> 6] = v;
    __syncthreads();

    if (threadIdx.x == 0) {
        int m = wmax[0];
#pragma unroll
        for (int w = 1; w < NUM_BINS / 64; ++w)
            m = max(m, wmax[w]);
        out[batch] = (float)m;
    }
}

extern "C" void kernel_launch(void* const* d_in, const int* in_sizes, int n_in,
                              void* d_out, int out_size, void* d_ws, size_t ws_size,
                              hipStream_t stream) {
    const int* in   = (const int*)d_in[0];
    float*     out  = (float*)d_out;
    int*       part = (int*)d_ws;   // B*BPB*256 ints = 512 KiB, fully overwritten

    const int B = out_size;         // 128

    percolation_hist_kernel<<<B * BPB, BLOCK1, 0, stream>>>(in, part);
    percolation_max_kernel<<<B, NUM_BINS, 0, stream>>>(part, out);
}